// Round 5
// baseline (120.944 us; speedup 1.0000x reference)
//
#include <hip/hip_runtime.h>
#include <cstdint>

typedef __bf16 bf16;
typedef __bf16 bf16x2 __attribute__((ext_vector_type(2)));
typedef __bf16 bf16x4 __attribute__((ext_vector_type(4)));
typedef __bf16 bf16x8 __attribute__((ext_vector_type(8)));
typedef float f32x4 __attribute__((ext_vector_type(4)));

constexpr int S = 2048, D = 1024, H = 16, HD = 64, B = 2;
constexpr size_t TSZ = (size_t)B * H * S * HD;  // 4 Mi elements

__device__ __forceinline__ f32x4 mfma16(bf16x8 a, bf16x8 b, f32x4 c) {
  return __builtin_amdgcn_mfma_f32_16x16x32_bf16(a, b, c, 0, 0, 0);
}

// async global->LDS, 16B per lane. LDS dest = wave-linear (base + lane*16).
__device__ __forceinline__ void gl_lds16(const bf16* g, bf16* s) {
  __builtin_amdgcn_global_load_lds((__attribute__((address_space(1))) void*)g,
                                   (__attribute__((address_space(3))) void*)s,
                                   16, 0, 0);
}

// ---------------------------------------------------------------------------
// prep: x fp32 -> bf16 (same layout)
// ---------------------------------------------------------------------------
__global__ __launch_bounds__(256) void prep_x(const float* __restrict__ x,
                                              bf16* __restrict__ xb) {
  const size_t i = (size_t)blockIdx.x * 256 + threadIdx.x;
  const float4 a = ((const float4*)x)[2 * i];
  const float4 b = ((const float4*)x)[2 * i + 1];
  bf16x8 o = {(bf16)a.x, (bf16)a.y, (bf16)a.z, (bf16)a.w,
              (bf16)b.x, (bf16)b.y, (bf16)b.z, (bf16)b.w};
  *(bf16x8*)&xb[i * 8] = o;
}

// ---------------------------------------------------------------------------
// prep: W [K][N] fp32 -> Wt [z][N][K] bf16 (transposed), 64x64 LDS tiles
// ---------------------------------------------------------------------------
__global__ __launch_bounds__(256) void prep_w(const float* __restrict__ W0,
                                              const float* __restrict__ W1,
                                              const float* __restrict__ W2,
                                              const float* __restrict__ W3,
                                              bf16* __restrict__ Wt) {
  __shared__ __align__(16) bf16 Lt[64][68];
  const int z = blockIdx.z;
  const float* W = z == 0 ? W0 : z == 1 ? W1 : z == 2 ? W2 : W3;
  const int k0 = blockIdx.x * 64, n0 = blockIdx.y * 64;
  const int t = threadIdx.x, tr = t >> 4, tc = (t & 15) * 4;
#pragma unroll
  for (int p = 0; p < 4; ++p) {
    const int r = 16 * p + tr;
    const float4 v = *(const float4*)&W[(size_t)(k0 + r) * D + n0 + tc];
    Lt[tc + 0][r] = (bf16)v.x;
    Lt[tc + 1][r] = (bf16)v.y;
    Lt[tc + 2][r] = (bf16)v.z;
    Lt[tc + 3][r] = (bf16)v.w;
  }
  __syncthreads();
#pragma unroll
  for (int p = 0; p < 4; ++p) {
    const int n = 16 * p + tr;
    const bf16x4 o = *(const bf16x4*)&Lt[n][tc];
    *(bf16x4*)&Wt[((size_t)z * D + n0 + n) * D + k0 + tc] = o;
  }
}

// ---------------------------------------------------------------------------
// bf16 GEMM, m97 structure: 128x128 tile, BK=64, 4 waves (2x2),
// global_load_lds staging with XOR-preswizzled source, swizzled b128 frags.
// A [M][K] bf16 row-major, Bt [N][K] bf16 row-major.
// MODE 0: C bf16 scattered to [3][B,H,S,Dh] (fused QKV). MODE 1: fp32 [M][D].
// ---------------------------------------------------------------------------
template <int MODE>
__global__ __launch_bounds__(256) void gemm_bt(const bf16* __restrict__ A,
                                               const bf16* __restrict__ Bt,
                                               void* __restrict__ Cp) {
  constexpr int K = 1024;
  __shared__ __align__(16) bf16 As[128 * 64];
  __shared__ __align__(16) bf16 Bs[128 * 64];

  const int bid = blockIdx.x, nwg = gridDim.x;       // nwg % 8 == 0
  const int lg = (bid & 7) * (nwg >> 3) + (bid >> 3);  // XCD-chunked
  const int bm = (lg & 31) * 128;
  const int bn = (lg >> 5) * 128;

  const int t = threadIdx.x, l = t & 63, w = t >> 6;
  const int c = l & 15, g = l >> 4, cx = c & 7;
  const int lrow = l >> 3;                  // row within 1KB LDS chunk
  const int srcc = ((l & 7) ^ lrow) << 3;   // pre-swizzled source k-offset
  const int wm = (w >> 1) * 64, wn = (w & 1) * 64;

  f32x4 acc[4][4] = {};

  for (int kt = 0; kt < K / 64; ++kt) {
    const int k0 = kt * 64;
    __syncthreads();  // prior compute done before overwrite
#pragma unroll
    for (int i = 0; i < 4; ++i) {
      const int ci = i * 4 + w;         // 1KB chunk id (16 per tile)
      const int row = ci * 8 + lrow;    // tile row 0..127
      gl_lds16(A + (size_t)(bm + row) * K + k0 + srcc, As + ci * 512 + l * 8);
      gl_lds16(Bt + (size_t)(bn + row) * K + k0 + srcc, Bs + ci * 512 + l * 8);
    }
    __syncthreads();  // drains vmcnt

    bf16x8 af[4][2], bfv[4][2];
#pragma unroll
    for (int mi = 0; mi < 4; ++mi) {
      const int row = wm + mi * 16 + c;  // row&7 == cx
#pragma unroll
      for (int kh = 0; kh < 2; ++kh)
        af[mi][kh] = *(const bf16x8*)&As[row * 64 + (((kh * 4 + g) ^ cx) << 3)];
    }
#pragma unroll
    for (int ni = 0; ni < 4; ++ni) {
      const int row = wn + ni * 16 + c;
#pragma unroll
      for (int kh = 0; kh < 2; ++kh)
        bfv[ni][kh] = *(const bf16x8*)&Bs[row * 64 + (((kh * 4 + g) ^ cx) << 3)];
    }
#pragma unroll
    for (int mi = 0; mi < 4; ++mi)
#pragma unroll
      for (int ni = 0; ni < 4; ++ni) {
        acc[mi][ni] = mfma16(af[mi][0], bfv[ni][0], acc[mi][ni]);
        acc[mi][ni] = mfma16(af[mi][1], bfv[ni][1], acc[mi][ni]);
      }
  }

  // epilogue: C frag row = 4g+r, col = c (verified mapping)
#pragma unroll
  for (int mi = 0; mi < 4; ++mi)
#pragma unroll
    for (int ni = 0; ni < 4; ++ni)
#pragma unroll
      for (int r = 0; r < 4; ++r) {
        const int m = bm + wm + mi * 16 + 4 * g + r;
        const int n = bn + wn + ni * 16 + c;
        const float v = acc[mi][ni][r];
        if constexpr (MODE == 0) {
          const int which = n >> 10, nn = n & 1023;
          const int h = nn >> 6, d = nn & 63;
          const int bb = m >> 11, s = m & 2047;
          ((bf16*)Cp)[which * TSZ + ((((size_t)bb * H + h) * S + s) << 6) + d] =
              (bf16)v;
        } else {
          ((float*)Cp)[(size_t)m * D + n] = v;
        }
      }
}

// ---------------------------------------------------------------------------
// Flash attention v5: uniform paired q-tiles + kv-split waves + in-reg P.
// Grid: 1024 blocks = 32 bh x 32 pairs. Block handles q-tiles (qp, 63-qp)
// of 32 rows each -> exactly 33 kv-tiles per block (uniform, no drain).
// 4 waves: (q-half h2 = w>>1) x (kv-half pk = w&1). Each wave: 16 q-rows,
// 32 kv per 64-tile, independent online softmax; partner waves merged per
// phase via LDS exchange (exact flash merge).
// S^T = mfma(K,Q): lane (g,c) holds S[kv=32pk+16ct+4g+r][q=c].
// PV: P packed in-register (bf16x8, permuted k-slots); V^T fragment read with
// the SAME kv permutation (2x ds_read_b64) -> no P LDS round-trip.
// ---------------------------------------------------------------------------
__global__ __launch_bounds__(256, 4) void attn5(const bf16* __restrict__ Q,
                                                const bf16* __restrict__ Kg,
                                                const bf16* __restrict__ Vg,
                                                bf16* __restrict__ O) {
  __shared__ __align__(16) unsigned char shraw[17408];
  bf16* Ks = (bf16*)shraw;             // [64][64] swizzled K, 8KB
  bf16* Vt = (bf16*)(shraw + 8192);    // [64][64] swizzled V^T, 8KB
  float* X = (float*)shraw;            // merge overlay [4][16][68] (17408B)

  const int bid = blockIdx.x;
  const int qp = bid >> 5, bh = bid & 31;   // bid%8 == bh%8 -> same-bh same XCD
  const int t = threadIdx.x, l = t & 63, w = t >> 6;
  const int h2 = w >> 1, pk = w & 1;
  const int c = l & 15, g = l >> 4, cx = c & 7;
  const int bb = bh >> 4, h = bh & 15;
  const float SC = 0.18033688011112042f;   // (1/8)*log2(e)
  const float THRS = 44.3614195558365f;    // 8 / SC

  const bf16* Kbase = Kg + (size_t)bh * S * HD;
  const bf16* Vbase = Vg + (size_t)bh * S * HD;

  const int kv0 = t >> 3, dg0 = t & 7, kv1 = kv0 + 32;  // K staging map
  const int p2 = t & 31, dgv = t >> 5;                  // V staging map

  for (int ph = 0; ph < 2; ++ph) {
    const int qt = ph ? (63 - qp) : qp;
    const int nT = (qt >> 1) + 1;            // kv-tiles this phase
    const int qglob = qt * 32 + 16 * h2 + c;

    const bf16* Qrow = Q + ((size_t)bh * S + qglob) * HD;
    const bf16x8 qf0 = *(const bf16x8*)&Qrow[g * 8];
    const bf16x8 qf1 = *(const bf16x8*)&Qrow[32 + g * 8];

    // prologue: tile 0 into regs
    bf16x8 ka0 = *(const bf16x8*)&Kbase[kv0 * 64 + dg0 * 8];
    bf16x8 ka1 = *(const bf16x8*)&Kbase[kv1 * 64 + dg0 * 8];
    bf16x8 va0 = *(const bf16x8*)&Vbase[(2 * p2) * 64 + dgv * 8];
    bf16x8 va1 = *(const bf16x8*)&Vbase[(2 * p2 + 1) * 64 + dgv * 8];

    f32x4 oacc[4] = {};
    float mrun = -1e30f, lrun = 0.f;

    for (int kt = 0; kt < nT; ++kt) {
      __syncthreads();  // prior LDS reads (and phase-A X reads) done
      // ---- regs -> LDS (K swizzled; V transposed, bf16x2 pairs) ----
      *(bf16x8*)&Ks[kv0 * 64 + ((dg0 ^ (kv0 & 7)) << 3)] = ka0;
      *(bf16x8*)&Ks[kv1 * 64 + ((dg0 ^ (kv1 & 7)) << 3)] = ka1;
#pragma unroll
      for (int i = 0; i < 8; ++i) {
        const int vd = 8 * dgv + i;  // vd&7 == i
        bf16x2 pr2 = {va0[i], va1[i]};
        *(bf16x2*)&Vt[vd * 64 + (((p2 >> 2) ^ i) << 3) + ((p2 & 3) << 1)] = pr2;
      }
      // ---- prefetch next tile into the same regs (store already consumed) ----
      if (kt + 1 < nT) {
        const bf16* Kt = Kbase + (size_t)(kt + 1) * 64 * HD;
        const bf16* Vs = Vbase + (size_t)(kt + 1) * 64 * HD;
        ka0 = *(const bf16x8*)&Kt[kv0 * 64 + dg0 * 8];
        ka1 = *(const bf16x8*)&Kt[kv1 * 64 + dg0 * 8];
        va0 = *(const bf16x8*)&Vs[(2 * p2) * 64 + dgv * 8];
        va1 = *(const bf16x8*)&Vs[(2 * p2 + 1) * 64 + dgv * 8];
      }
      __syncthreads();

      // ---- S^T = K Q^T over this wave's 32-kv half ----
      f32x4 st[2];
      __builtin_amdgcn_s_setprio(1);
#pragma unroll
      for (int ct = 0; ct < 2; ++ct) {
        const int krow = 32 * pk + 16 * ct + c;  // krow&7 == cx
        const bf16x8 kf0 = *(const bf16x8*)&Ks[krow * 64 + ((g ^ cx) << 3)];
        const bf16x8 kf1 = *(const bf16x8*)&Ks[krow * 64 + (((4 + g) ^ cx) << 3)];
        f32x4 z = {};
        z = mfma16(kf0, qf0, z);
        st[ct] = mfma16(kf1, qf1, z);
      }
      __builtin_amdgcn_s_setprio(0);

      if (kt == nT - 1) {  // causal mask (only last tile can cross diagonal)
#pragma unroll
        for (int ct = 0; ct < 2; ++ct)
#pragma unroll
          for (int r = 0; r < 4; ++r)
            if (kt * 64 + 32 * pk + 16 * ct + 4 * g + r > qglob)
              st[ct][r] = -3e38f;
      }

      // ---- in-lane online softmax over 8 values + defer-max ----
      float mt = st[0][0];
#pragma unroll
      for (int ct = 0; ct < 2; ++ct)
#pragma unroll
        for (int r = 0; r < 4; ++r) mt = fmaxf(mt, st[ct][r]);
      mt = fmaxf(mt, __shfl_xor(mt, 16));
      mt = fmaxf(mt, __shfl_xor(mt, 32));
      if (!__all(mt <= mrun + THRS)) {
        const float mnew = fmaxf(mrun, mt);
        const float fac = __builtin_amdgcn_exp2f((mrun - mnew) * SC);
        lrun *= fac;
#pragma unroll
        for (int q = 0; q < 4; ++q)
#pragma unroll
          for (int r = 0; r < 4; ++r) oacc[q][r] *= fac;
        mrun = mnew;
      }
      float p[2][4];
      float ps = 0.f;
#pragma unroll
      for (int ct = 0; ct < 2; ++ct)
#pragma unroll
        for (int r = 0; r < 4; ++r) {
          p[ct][r] = __builtin_amdgcn_exp2f((st[ct][r] - mrun) * SC);
          ps += p[ct][r];
        }
      ps += __shfl_xor(ps, 16);
      ps += __shfl_xor(ps, 32);
      lrun += ps;

      // ---- P in-register (k-slot order: kv = 32pk + 16(i>>2) + 4g + (i&3)) ----
      const bf16x8 pa = {(bf16)p[0][0], (bf16)p[0][1], (bf16)p[0][2], (bf16)p[0][3],
                         (bf16)p[1][0], (bf16)p[1][1], (bf16)p[1][2], (bf16)p[1][3]};

      // ---- O^T += V^T P^T (V frag read with the same kv permutation) ----
      __builtin_amdgcn_s_setprio(1);
#pragma unroll
      for (int cp = 0; cp < 4; ++cp) {
        const int vb = (16 * cp + c) * 64;  // vd&7 == cx
        const bf16x4 lo = *(const bf16x4*)&Vt[vb + ((((pk << 2) + (g >> 1)) ^ cx) << 3) + ((g & 1) << 2)];
        const bf16x4 hi = *(const bf16x4*)&Vt[vb + ((((pk << 2) + 2 + (g >> 1)) ^ cx) << 3) + ((g & 1) << 2)];
        const bf16x8 vf = {lo[0], lo[1], lo[2], lo[3], hi[0], hi[1], hi[2], hi[3]};
        oacc[cp] = mfma16(vf, pa, oacc[cp]);
      }
      __builtin_amdgcn_s_setprio(0);
    }

    // ---- merge kv-half partials (waves (h2,0) <-> (h2,1)), store output ----
    __syncthreads();  // all PV reads done before overlay write
    float* Xw = X + w * (16 * 68);
#pragma unroll
    for (int cp = 0; cp < 4; ++cp)
      *(f32x4*)&Xw[c * 68 + 16 * cp + 4 * g] = oacc[cp];
    if (g == 0) { Xw[c * 68 + 64] = mrun; Xw[c * 68 + 65] = lrun; }
    __syncthreads();
    const float* Xp = X + (w ^ 1) * (16 * 68);
    const float m2 = Xp[c * 68 + 64], l2 = Xp[c * 68 + 65];
    const float mn = fmaxf(mrun, m2);
    const float f1 = __builtin_amdgcn_exp2f((mrun - mn) * SC);
    const float f2 = __builtin_amdgcn_exp2f((m2 - mn) * SC);
    const float linv = 1.f / (lrun * f1 + l2 * f2);
    bf16* Orow = O + ((size_t)bb * S + qglob) * D + h * 64;
#pragma unroll
    for (int j = 0; j < 2; ++j) {
      const int cp = 2 * pk + j;  // this wave stores its 2 d-quarters
      const f32x4 o2 = *(const f32x4*)&Xp[c * 68 + 16 * cp + 4 * g];
#pragma unroll
      for (int pr = 0; pr < 2; ++pr) {
        bf16x2 pkk = {(bf16)((oacc[cp][2 * pr] * f1 + o2[2 * pr] * f2) * linv),
                      (bf16)((oacc[cp][2 * pr + 1] * f1 + o2[2 * pr + 1] * f2) * linv)};
        *(bf16x2*)&Orow[16 * cp + 4 * g + 2 * pr] = pkk;
      }
    }
    // next phase's first __syncthreads protects X before restaging
  }
}

// ---------------------------------------------------------------------------
extern "C" void kernel_launch(void* const* d_in, const int* in_sizes, int n_in,
                              void* d_out, int out_size, void* d_ws, size_t ws_size,
                              hipStream_t stream) {
  const float* x  = (const float*)d_in[0];
  const float* Wq = (const float*)d_in[1];
  const float* Wk = (const float*)d_in[2];
  const float* Wv = (const float*)d_in[3];
  const float* Wo = (const float*)d_in[4];
  float* out = (float*)d_out;

  bf16* xb  = (bf16*)d_ws;                       // 4Mi  (8 MB)
  bf16* Wt  = xb + (size_t)B * S * D;            // 4Mi  (8 MB) [4][1024][1024]
  bf16* QKV = Wt + (size_t)4 * D * D;            // 12Mi (24 MB) [3][B,H,S,Dh]
  bf16* Ab  = QKV + 3 * TSZ;                     // 4Mi  (8 MB) [B*S][D]

  prep_x<<<2048, 256, 0, stream>>>(x, xb);
  prep_w<<<dim3(16, 16, 4), 256, 0, stream>>>(Wq, Wk, Wv, Wo, Wt);
  gemm_bt<0><<<768, 256, 0, stream>>>(xb, Wt, QKV);                  // fused QKV
  attn5<<<1024, 256, 0, stream>>>(QKV, QKV + TSZ, QKV + 2 * TSZ, Ab);
  gemm_bt<1><<<256, 256, 0, stream>>>(Ab, Wt + (size_t)3 * D * D, out);
}